// Round 16
// baseline (197.856 us; speedup 1.0000x reference)
//
#include <hip/hip_runtime.h>
#include <math.h>

#define N_NODES 4096
#define F_IN    512
#define F_OUT   64
#define ALPHA   0.2f
#define NPART   8

typedef _Float16 half8 __attribute__((ext_vector_type(8)));
typedef _Float16 half4 __attribute__((ext_vector_type(4)));
typedef float    floatx4 __attribute__((ext_vector_type(4)));

union H8U4 { half8 h; uint32_t u[4]; };

// async global->LDS DMA, 16B per lane, dest = lds_base + lane*16 (wave-uniform base)
__device__ __forceinline__ void async_copy16(void* lds, const void* g) {
    __builtin_amdgcn_global_load_lds(
        (const __attribute__((address_space(1))) unsigned int*)g,
        (__attribute__((address_space(3))) unsigned int*)lds, 16, 0, 0);
}

// ---------------- k_prep: WT[t][k] = f16(W[k][t]) (64x512); zero rb-counters ----------------
__global__ __launch_bounds__(256) void k_prep(const float* __restrict__ W,
                                              _Float16* __restrict__ WT,
                                              unsigned int* __restrict__ counters) {
    int idx = blockIdx.x * 256 + threadIdx.x;   // 32768 total
    int t = idx >> 9;
    int k = idx & 511;
    WT[idx] = (_Float16)W[k * F_OUT + t];
    if (blockIdx.x == 0 && threadIdx.x < 64) counters[threadIdx.x] = 0u;
}

// ---------------- k_hW: h = x@W via MFMA (K-split across 4 waves); h, hT(f16), e1 ----------------
__global__ __launch_bounds__(256) void k_hW(const float* __restrict__ x,
                                            const _Float16* __restrict__ WT,
                                            const float* __restrict__ a,
                                            float* __restrict__ h,
                                            _Float16* __restrict__ hT,
                                            float* __restrict__ e1) {
    __shared__ float red[4][16][64];   // [wave][g4*4+r][lane]
    int tid  = threadIdx.x;
    int lane = tid & 63;
    int w    = tid >> 6;
    int i0   = blockIdx.x * 16;
    int n    = lane & 15;
    int quad = lane >> 4;

    floatx4 acc[4] = {{0,0,0,0},{0,0,0,0},{0,0,0,0},{0,0,0,0}};

    const float* xr = x + (size_t)(i0 + n) * F_IN + w * 128 + quad * 8;
    const _Float16* wb = WT + w * 128 + quad * 8;
#pragma unroll
    for (int kk = 0; kk < 128; kk += 32) {
        float4 x0 = *(const float4*)(xr + kk);
        float4 x1 = *(const float4*)(xr + kk + 4);
        half8 af = {(_Float16)x0.x, (_Float16)x0.y, (_Float16)x0.z, (_Float16)x0.w,
                    (_Float16)x1.x, (_Float16)x1.y, (_Float16)x1.z, (_Float16)x1.w};
#pragma unroll
        for (int g = 0; g < 4; ++g) {
            half8 bf = *(const half8*)(wb + (size_t)(g * 16 + n) * F_IN + kk);
            acc[g] = __builtin_amdgcn_mfma_f32_16x16x32_f16(af, bf, acc[g], 0, 0, 0);
        }
    }
#pragma unroll
    for (int g = 0; g < 4; ++g)
#pragma unroll
        for (int r = 0; r < 4; ++r)
            red[w][g * 4 + r][lane] = acc[g][r];
    __syncthreads();
    if (w != 0) return;
#pragma unroll
    for (int g = 0; g < 4; ++g)
#pragma unroll
        for (int r = 0; r < 4; ++r)
            acc[g][r] = red[0][g * 4 + r][lane] + red[1][g * 4 + r][lane] +
                        red[2][g * 4 + r][lane] + red[3][g * 4 + r][lane];
#pragma unroll
    for (int g = 0; g < 4; ++g) {
        half4 hv;
#pragma unroll
        for (int r = 0; r < 4; ++r) {
            h[(size_t)(i0 + quad * 4 + r) * F_OUT + g * 16 + n] = acc[g][r];
            hv[r] = (_Float16)acc[g][r];
        }
        *(half4*)(hT + (size_t)(g * 16 + n) * N_NODES + i0 + quad * 4) = hv;
    }
    float a1v[4];
#pragma unroll
    for (int g = 0; g < 4; ++g) a1v[g] = a[g * 16 + n];
#pragma unroll
    for (int r = 0; r < 4; ++r) {
        float v = acc[0][r] * a1v[0] + acc[1][r] * a1v[1] + acc[2][r] * a1v[2] + acc[3][r] * a1v[3];
        v += __shfl_xor(v, 1, 64);
        v += __shfl_xor(v, 2, 64);
        v += __shfl_xor(v, 4, 64);
        v += __shfl_xor(v, 8, 64);
        if (n == 0) e1[i0 + quad * 4 + r] = v;
    }
}

// ---------------- k_main: fused Tq/P + DMA-staged masked MFMA + last-block epilogue ----------------
// grid 512: b -> rb = b>>3 (64-row block), s = b&7 (512-col superchunk = 4x128).
__global__ __launch_bounds__(256, 3) void k_main(const int* __restrict__ adj,
                                                 const float* __restrict__ h,
                                                 const float* __restrict__ e1,
                                                 const float* __restrict__ a,
                                                 const _Float16* __restrict__ hT,
                                                 float* __restrict__ out_part,
                                                 float* __restrict__ den_part,
                                                 unsigned int* __restrict__ counters,
                                                 const float* __restrict__ bias,
                                                 float* __restrict__ out) {
    __shared__ int      lds_adj[4][8][256];   // 32 KB
    __shared__ _Float16 lds_B[16][512];       // 16 KB
    __shared__ _Float16 lds_P[512];           //  1 KB
    __shared__ float    lds_part[4][64];      //  1 KB
    __shared__ float    TqS[64];
    __shared__ unsigned int s_old;

    int tid  = threadIdx.x;
    int lane = tid & 63;
    int w    = tid >> 6;
    int b    = blockIdx.x;
    int rb   = b >> 3;
    int s    = b & 7;
    int i0   = rb * 64 + w * 16;
    int n    = lane & 15;
    int quad = lane >> 4;

    // ---- prologue: Tq[rb][t] = sum_r a2[r] * h[(r*64+rb)*64 + t] ----
    {
        int t  = tid & 63;
        int rp = tid >> 6;
        const float* a2 = a + F_OUT;
        float ssum = 0.f;
#pragma unroll
        for (int rr = 0; rr < 16; ++rr) {
            int r = rp * 16 + rr;
            ssum += a2[r] * h[(size_t)r * 4096 + rb * 64 + t];
        }
        lds_part[rp][t] = ssum;
    }
    __syncthreads();
    if (tid < 64)
        TqS[tid] = lds_part[0][tid] + lds_part[1][tid] + lds_part[2][tid] + lds_part[3][tid];
    __syncthreads();
    {
        int j = s * 512 + tid * 2;
        float2 ev = *(const float2*)(e1 + j);
        float e0 = ev.x + TqS[(tid * 2) & 63];
        float e1v = ev.y + TqS[(tid * 2 + 1) & 63];
        e0  = e0  > 0.f ? e0  : ALPHA * e0;
        e1v = e1v > 0.f ? e1v : ALPHA * e1v;
        lds_P[tid * 2]     = (_Float16)__expf(e0);
        lds_P[tid * 2 + 1] = (_Float16)__expf(e1v);
    }
    // first use of lds_P is after the first chunk's __syncthreads()

    floatx4 acc[4] = {{0,0,0,0},{0,0,0,0},{0,0,0,0},{0,0,0,0}};
    floatx4 accd = {0, 0, 0, 0};
    _Float16 one_h = (n == 0) ? (_Float16)1.0f : (_Float16)0.0f;
    half8 ones_f = {one_h, one_h, one_h, one_h, one_h, one_h, one_h, one_h};

    for (int it = 0; it < 4; ++it) {
        int jb = s * 512 + it * 128;
        const int* adj_base = adj + (size_t)(i0 + n) * N_NODES + jb + quad * 8;
#pragma unroll
        for (int c = 0; c < 4; ++c) {
            async_copy16(&lds_adj[w][c * 2 + 0][0], adj_base + c * 32);
            async_copy16(&lds_adj[w][c * 2 + 1][0], adj_base + c * 32 + 4);
        }
        const _Float16* hT_base = hT + (size_t)(w * 16 + n) * N_NODES + jb + quad * 8;
#pragma unroll
        for (int c = 0; c < 4; ++c)
            async_copy16(&lds_B[w * 4 + c][0], hT_base + c * 32);
        __syncthreads();

#pragma unroll
        for (int c = 0; c < 4; ++c) {
            int4 ga = *(const int4*)&lds_adj[w][c * 2 + 0][lane * 4];
            int4 gb = *(const int4*)&lds_adj[w][c * 2 + 1][lane * 4];
            H8U4 pv, af;
            pv.h = *(const half8*)&lds_P[it * 128 + c * 32 + quad * 8];
            af.u[0] = pv.u[0] & ((ga.x > 0 ? 0x0000FFFFu : 0u) | (ga.y > 0 ? 0xFFFF0000u : 0u));
            af.u[1] = pv.u[1] & ((ga.z > 0 ? 0x0000FFFFu : 0u) | (ga.w > 0 ? 0xFFFF0000u : 0u));
            af.u[2] = pv.u[2] & ((gb.x > 0 ? 0x0000FFFFu : 0u) | (gb.y > 0 ? 0xFFFF0000u : 0u));
            af.u[3] = pv.u[3] & ((gb.z > 0 ? 0x0000FFFFu : 0u) | (gb.w > 0 ? 0xFFFF0000u : 0u));
#pragma unroll
            for (int g4 = 0; g4 < 4; ++g4) {
                half8 bf = *(const half8*)&lds_B[g4 * 4 + c][lane * 8];
                acc[g4] = __builtin_amdgcn_mfma_f32_16x16x32_f16(af.h, bf, acc[g4], 0, 0, 0);
            }
            accd = __builtin_amdgcn_mfma_f32_16x16x32_f16(af.h, ones_f, accd, 0, 0, 0);
        }
        __syncthreads();
    }

    // ---- store this superchunk's private partial ----
    float* op = out_part + ((size_t)s * N_NODES + i0) * F_OUT;
#pragma unroll
    for (int g4 = 0; g4 < 4; ++g4)
#pragma unroll
        for (int r = 0; r < 4; ++r)
            op[(quad * 4 + r) * F_OUT + g4 * 16 + n] = acc[g4][r];
    if (n == 0) {
#pragma unroll
        for (int r = 0; r < 4; ++r)
            den_part[s * N_NODES + i0 + quad * 4 + r] = accd[r];
    }

    // ---- last-block-of-rb epilogue: relu(sum_p out_part / sum_p den_part) + bias -> out ----
    __threadfence();                       // release: partials visible device-wide
    if (tid == 0) s_old = atomicAdd(&counters[rb], 1u);
    __syncthreads();
    if (s_old != NPART - 1) return;
    __threadfence();                       // acquire: see all 8 blocks' partials

#pragma unroll
    for (int k2 = 0; k2 < 4; ++k2) {
        int idx4 = k2 * 256 + tid;         // 1024 float4s = 64 rows x 16
        int il = idx4 >> 4;                // local row 0..63
        int t4 = (idx4 & 15) * 4;
        int gi = rb * 64 + il;
        float4 sacc = {0.f, 0.f, 0.f, 0.f};
        float dacc = 0.f;
#pragma unroll
        for (int p = 0; p < NPART; ++p) {
            float4 v = *(const float4*)(out_part + ((size_t)p * N_NODES + gi) * F_OUT + t4);
            sacc.x += v.x; sacc.y += v.y; sacc.z += v.z; sacc.w += v.w;
            dacc += den_part[p * N_NODES + gi];
        }
        float4 bv = *(const float4*)(bias + t4);
        float4 o;
        o.x = fmaxf(sacc.x / dacc, 0.f) + bv.x;
        o.y = fmaxf(sacc.y / dacc, 0.f) + bv.y;
        o.z = fmaxf(sacc.z / dacc, 0.f) + bv.z;
        o.w = fmaxf(sacc.w / dacc, 0.f) + bv.w;
        *(float4*)(out + (size_t)gi * F_OUT + t4) = o;
    }
}

extern "C" void kernel_launch(void* const* d_in, const int* in_sizes, int n_in,
                              void* d_out, int out_size, void* d_ws, size_t ws_size,
                              hipStream_t stream) {
    const float* x    = (const float*)d_in[0];
    const int*   adj  = (const int*)d_in[1];
    const float* W    = (const float*)d_in[2];
    const float* a    = (const float*)d_in[3];
    const float* bias = (const float*)d_in[4];
    float* out = (float*)d_out;

    char* ws = (char*)d_ws;
    float*    h        = (float*)ws;                            // 1 MB
    _Float16* hT       = (_Float16*)(ws + 1024 * 1024);         // 512 KB
    float*    e1       = (float*)(ws + 1536 * 1024);            // 16 KB
    _Float16* WT       = (_Float16*)(ws + 1552 * 1024);         // 64 KB
    float*    out_part = (float*)(ws + 2128 * 1024);            // 8 MB (NPART=8, fp32)
    float*    den_part = (float*)(ws + (2128 + 8192) * 1024);   // 128 KB
    unsigned int* counters = (unsigned int*)(ws + (2128 + 8192 + 128) * 1024); // 256 B

    k_prep<<<128, 256, 0, stream>>>(W, WT, counters);
    k_hW  <<<256, 256, 0, stream>>>(x, WT, a, h, hT, e1);
    k_main<<<512, 256, 0, stream>>>(adj, h, e1, a, hT, out_part, den_part, counters, bias, out);
}

// Round 18
// 119.300 us; speedup vs baseline: 1.6585x; 1.6585x over previous
//
#include <hip/hip_runtime.h>
#include <math.h>

#define N_NODES 4096
#define F_IN    512
#define F_OUT   64
#define ALPHA   0.2f
#define NPART   8

typedef _Float16 half8 __attribute__((ext_vector_type(8)));
typedef _Float16 half4 __attribute__((ext_vector_type(4)));
typedef float    floatx4 __attribute__((ext_vector_type(4)));

union H8U4 { half8 h; uint32_t u[4]; };

// async global->LDS DMA, 16B per lane, dest = lds_base + lane*16 (wave-uniform base)
__device__ __forceinline__ void async_copy16(void* lds, const void* g) {
    __builtin_amdgcn_global_load_lds(
        (const __attribute__((address_space(1))) unsigned int*)g,
        (__attribute__((address_space(3))) unsigned int*)lds, 16, 0, 0);
}

// ---------------- k_prep: WT[t][k] = f16(W[k][t])  (64 x 512) ----------------
__global__ __launch_bounds__(256) void k_prep(const float* __restrict__ W,
                                              _Float16* __restrict__ WT) {
    int idx = blockIdx.x * 256 + threadIdx.x;   // 32768 total
    int t = idx >> 9;
    int k = idx & 511;
    WT[idx] = (_Float16)W[k * F_OUT + t];
}

// ---------------- k_hW: h = x@W via MFMA, K-split across 8 waves (512-thr blocks) ----------------
// grid 256: block = 16 rows; wave w (0..7) covers K slice [w*64, w*64+64). 8 waves/CU.
__global__ __launch_bounds__(512) void k_hW(const float* __restrict__ x,
                                            const _Float16* __restrict__ WT,
                                            const float* __restrict__ a,
                                            float* __restrict__ h,
                                            _Float16* __restrict__ hT,
                                            float* __restrict__ e1) {
    __shared__ float red[8][16][64];   // [wave][g4*4+r][lane]  32 KB
    int tid  = threadIdx.x;
    int lane = tid & 63;
    int w    = tid >> 6;               // 0..7
    int i0   = blockIdx.x * 16;
    int n    = lane & 15;
    int quad = lane >> 4;

    floatx4 acc[4] = {{0,0,0,0},{0,0,0,0},{0,0,0,0},{0,0,0,0}};

    const float* xr = x + (size_t)(i0 + n) * F_IN + w * 64 + quad * 8;
    const _Float16* wb = WT + w * 64 + quad * 8;
#pragma unroll
    for (int kk = 0; kk < 64; kk += 32) {
        float4 x0 = *(const float4*)(xr + kk);
        float4 x1 = *(const float4*)(xr + kk + 4);
        half8 af = {(_Float16)x0.x, (_Float16)x0.y, (_Float16)x0.z, (_Float16)x0.w,
                    (_Float16)x1.x, (_Float16)x1.y, (_Float16)x1.z, (_Float16)x1.w};
#pragma unroll
        for (int g = 0; g < 4; ++g) {
            half8 bf = *(const half8*)(wb + (size_t)(g * 16 + n) * F_IN + kk);
            acc[g] = __builtin_amdgcn_mfma_f32_16x16x32_f16(af, bf, acc[g], 0, 0, 0);
        }
    }
#pragma unroll
    for (int g = 0; g < 4; ++g)
#pragma unroll
        for (int r = 0; r < 4; ++r)
            red[w][g * 4 + r][lane] = acc[g][r];
    __syncthreads();
    if (w != 0) return;
#pragma unroll
    for (int g = 0; g < 4; ++g)
#pragma unroll
        for (int r = 0; r < 4; ++r) {
            float v = 0.f;
#pragma unroll
            for (int ww = 0; ww < 8; ++ww)
                v += red[ww][g * 4 + r][lane];
            acc[g][r] = v;
        }
#pragma unroll
    for (int g = 0; g < 4; ++g) {
        half4 hv;
#pragma unroll
        for (int r = 0; r < 4; ++r) {
            h[(size_t)(i0 + quad * 4 + r) * F_OUT + g * 16 + n] = acc[g][r];
            hv[r] = (_Float16)acc[g][r];
        }
        *(half4*)(hT + (size_t)(g * 16 + n) * N_NODES + i0 + quad * 4) = hv;
    }
    float a1v[4];
#pragma unroll
    for (int g = 0; g < 4; ++g) a1v[g] = a[g * 16 + n];
#pragma unroll
    for (int r = 0; r < 4; ++r) {
        float v = acc[0][r] * a1v[0] + acc[1][r] * a1v[1] + acc[2][r] * a1v[2] + acc[3][r] * a1v[3];
        v += __shfl_xor(v, 1, 64);
        v += __shfl_xor(v, 2, 64);
        v += __shfl_xor(v, 4, 64);
        v += __shfl_xor(v, 8, 64);
        if (n == 0) e1[i0 + quad * 4 + r] = v;
    }
}

// ---------------- k_main: FUSED Tq/P compute + DMA-staged masked MFMA, 4-chunk K-loop ----------------
// grid 512: b -> rb = b>>3 (64-row block), s = b&7 (512-col superchunk = 4x128).
__global__ __launch_bounds__(256, 3) void k_main(const int* __restrict__ adj,
                                                 const float* __restrict__ h,
                                                 const float* __restrict__ e1,
                                                 const float* __restrict__ a,
                                                 const _Float16* __restrict__ hT,
                                                 float* __restrict__ out_part,
                                                 float* __restrict__ den_part) {
    __shared__ int      lds_adj[4][8][256];   // 32 KB
    __shared__ _Float16 lds_B[16][512];       // 16 KB
    __shared__ _Float16 lds_P[512];           //  1 KB
    __shared__ float    lds_part[4][64];      //  1 KB
    __shared__ float    TqS[64];

    int tid  = threadIdx.x;
    int lane = tid & 63;
    int w    = tid >> 6;
    int b    = blockIdx.x;
    int rb   = b >> 3;
    int s    = b & 7;
    int i0   = rb * 64 + w * 16;
    int n    = lane & 15;
    int quad = lane >> 4;

    // ---- prologue: Tq[rb][t] = sum_r a2[r] * h[(r*64+rb)*64 + t] ----
    {
        int t  = tid & 63;
        int rp = tid >> 6;
        const float* a2 = a + F_OUT;
        float ssum = 0.f;
#pragma unroll
        for (int rr = 0; rr < 16; ++rr) {
            int r = rp * 16 + rr;
            ssum += a2[r] * h[(size_t)r * 4096 + rb * 64 + t];
        }
        lds_part[rp][t] = ssum;
    }
    __syncthreads();
    if (tid < 64)
        TqS[tid] = lds_part[0][tid] + lds_part[1][tid] + lds_part[2][tid] + lds_part[3][tid];
    __syncthreads();
    {
        int j = s * 512 + tid * 2;
        float2 ev = *(const float2*)(e1 + j);
        float e0 = ev.x + TqS[(tid * 2) & 63];
        float e1v = ev.y + TqS[(tid * 2 + 1) & 63];
        e0  = e0  > 0.f ? e0  : ALPHA * e0;
        e1v = e1v > 0.f ? e1v : ALPHA * e1v;
        lds_P[tid * 2]     = (_Float16)__expf(e0);
        lds_P[tid * 2 + 1] = (_Float16)__expf(e1v);
    }
    // first use of lds_P is after the first chunk's __syncthreads()

    floatx4 acc[4] = {{0,0,0,0},{0,0,0,0},{0,0,0,0},{0,0,0,0}};
    floatx4 accd = {0, 0, 0, 0};
    _Float16 one_h = (n == 0) ? (_Float16)1.0f : (_Float16)0.0f;
    half8 ones_f = {one_h, one_h, one_h, one_h, one_h, one_h, one_h, one_h};

    for (int it = 0; it < 4; ++it) {
        int jb = s * 512 + it * 128;
        const int* adj_base = adj + (size_t)(i0 + n) * N_NODES + jb + quad * 8;
#pragma unroll
        for (int c = 0; c < 4; ++c) {
            async_copy16(&lds_adj[w][c * 2 + 0][0], adj_base + c * 32);
            async_copy16(&lds_adj[w][c * 2 + 1][0], adj_base + c * 32 + 4);
        }
        const _Float16* hT_base = hT + (size_t)(w * 16 + n) * N_NODES + jb + quad * 8;
#pragma unroll
        for (int c = 0; c < 4; ++c)
            async_copy16(&lds_B[w * 4 + c][0], hT_base + c * 32);
        __syncthreads();

#pragma unroll
        for (int c = 0; c < 4; ++c) {
            int4 ga = *(const int4*)&lds_adj[w][c * 2 + 0][lane * 4];
            int4 gb = *(const int4*)&lds_adj[w][c * 2 + 1][lane * 4];
            H8U4 pv, af;
            pv.h = *(const half8*)&lds_P[it * 128 + c * 32 + quad * 8];
            af.u[0] = pv.u[0] & ((ga.x > 0 ? 0x0000FFFFu : 0u) | (ga.y > 0 ? 0xFFFF0000u : 0u));
            af.u[1] = pv.u[1] & ((ga.z > 0 ? 0x0000FFFFu : 0u) | (ga.w > 0 ? 0xFFFF0000u : 0u));
            af.u[2] = pv.u[2] & ((gb.x > 0 ? 0x0000FFFFu : 0u) | (gb.y > 0 ? 0xFFFF0000u : 0u));
            af.u[3] = pv.u[3] & ((gb.z > 0 ? 0x0000FFFFu : 0u) | (gb.w > 0 ? 0xFFFF0000u : 0u));
#pragma unroll
            for (int g4 = 0; g4 < 4; ++g4) {
                half8 bf = *(const half8*)&lds_B[g4 * 4 + c][lane * 8];
                acc[g4] = __builtin_amdgcn_mfma_f32_16x16x32_f16(af.h, bf, acc[g4], 0, 0, 0);
            }
            accd = __builtin_amdgcn_mfma_f32_16x16x32_f16(af.h, ones_f, accd, 0, 0, 0);
        }
        __syncthreads();
    }

    // ---- store this superchunk's private partial (C: row = quad*4+r, col = g4*16+n) ----
    float* op = out_part + ((size_t)s * N_NODES + i0) * F_OUT;
#pragma unroll
    for (int g4 = 0; g4 < 4; ++g4)
#pragma unroll
        for (int r = 0; r < 4; ++r)
            op[(quad * 4 + r) * F_OUT + g4 * 16 + n] = acc[g4][r];
    if (n == 0) {
#pragma unroll
        for (int r = 0; r < 4; ++r)
            den_part[s * N_NODES + i0 + quad * 4 + r] = accd[r];
    }
}

// ---------------- k_out: out = relu(sum_s out_part / sum_s den_part) + bias (float4) ----------------
__global__ __launch_bounds__(128) void k_out(const float* __restrict__ out_part,
                                             const float* __restrict__ den_part,
                                             const float* __restrict__ bias,
                                             float* __restrict__ out) {
    int idx4 = blockIdx.x * 128 + threadIdx.x;   // 65536 float4s
    int base = idx4 * 4;
    int i = base >> 6;
    int t = base & 63;
    float4 sacc = {0.f, 0.f, 0.f, 0.f};
    float dacc = 0.f;
#pragma unroll
    for (int p = 0; p < NPART; ++p) {
        float4 v = ((const float4*)(out_part + (size_t)p * N_NODES * F_OUT))[idx4];
        sacc.x += v.x; sacc.y += v.y; sacc.z += v.z; sacc.w += v.w;
        dacc += den_part[p * N_NODES + i];
    }
    float4 bv = *(const float4*)(bias + t);
    float4 o;
    o.x = fmaxf(sacc.x / dacc, 0.f) + bv.x;
    o.y = fmaxf(sacc.y / dacc, 0.f) + bv.y;
    o.z = fmaxf(sacc.z / dacc, 0.f) + bv.z;
    o.w = fmaxf(sacc.w / dacc, 0.f) + bv.w;
    ((float4*)out)[idx4] = o;
}

extern "C" void kernel_launch(void* const* d_in, const int* in_sizes, int n_in,
                              void* d_out, int out_size, void* d_ws, size_t ws_size,
                              hipStream_t stream) {
    const float* x    = (const float*)d_in[0];
    const int*   adj  = (const int*)d_in[1];
    const float* W    = (const float*)d_in[2];
    const float* a    = (const float*)d_in[3];
    const float* bias = (const float*)d_in[4];
    float* out = (float*)d_out;

    char* ws = (char*)d_ws;
    float*    h        = (float*)ws;                            // 1 MB
    _Float16* hT       = (_Float16*)(ws + 1024 * 1024);         // 512 KB
    float*    e1       = (float*)(ws + 1536 * 1024);            // 16 KB
    _Float16* WT       = (_Float16*)(ws + 1552 * 1024);         // 64 KB
    float*    out_part = (float*)(ws + 2128 * 1024);            // 8 MB (NPART=8, fp32)
    float*    den_part = (float*)(ws + (2128 + 8192) * 1024);   // 128 KB

    k_prep<<<128, 256, 0, stream>>>(W, WT);
    k_hW  <<<256, 512, 0, stream>>>(x, WT, a, h, hT, e1);
    k_main<<<512, 256, 0, stream>>>(adj, h, e1, a, hT, out_part, den_part);
    k_out <<<512, 128, 0, stream>>>(out_part, den_part, bias, out);
}